// Round 8
// baseline (554.400 us; speedup 1.0000x reference)
//
#include <hip/hip_runtime.h>
#include <hip/hip_cooperative_groups.h>
#include <hip/hip_bf16.h>
#include <stdint.h>

namespace cg = cooperative_groups;

#define B_ 2
#define N_ 2048
#define D_ 1024
#define H_ 16
#define HD_ 64
#define INNER_ 1024
#define HALF_W 128

typedef unsigned short u16;
typedef __attribute__((ext_vector_type(8))) short short8;
typedef __attribute__((ext_vector_type(4))) float floatx4;

// ---- bf16 <-> f32 bit helpers ----
__device__ inline u16 f2bu(float x) {
    union { float f; uint32_t u; } c; c.f = x;
    uint32_t u = c.u;
    uint32_t r = (u + 0x7FFFu + ((u >> 16) & 1u)) >> 16;
    return (u16)r;
}
__device__ inline float bu2f(u16 v) {
    union { float f; uint32_t u; } c; c.u = ((uint32_t)v) << 16;
    return c.f;
}

// ---- async global->LDS, 16B per lane (dest = wave-uniform base + lane*16) ----
__device__ inline void glds16(const u16* g, u16* l) {
    __builtin_amdgcn_global_load_lds(
        (const __attribute__((address_space(1))) uint32_t*)g,
        (__attribute__((address_space(3))) uint32_t*)l, 16, 0, 0);
}

struct MegaArgs {
    const float *x, *Wq, *Wk, *Wv, *Wo, *bq, *bk, *bv, *bo, *freqs;
    u16 *xb, *wqkvt, *wot;
    float *bias_qkv, *bias_o;
    u16 *Qg, *Kg, *Vtg, *attn;
    float *out;
};

// ================  single cooperative kernel: prep | qkv-gemm | attn | out-gemm  ================
__global__ __launch_bounds__(256, 4) void k_mega(MegaArgs a) {
    __shared__ __align__(16) u16 smem[17664];   // 35328 B, unioned across phases
    const int t = threadIdx.x;
    const int gdim = gridDim.x;
    const int wave = t >> 6, lane = t & 63;
    const int quad = lane >> 4, l16 = lane & 15;

    // ================= phase 1: prep (2049 vblocks) =================
    {
        float* ts = (float*)smem;               // [64][65]
        for (int bx = blockIdx.x; bx < 2049; bx += gdim) {
            __syncthreads();                    // ts reuse across grid-stride iters
            if (bx < 1024) {
                const int z = bx >> 8, wv = bx & 255;
                const int kb = wv & 15, nb2 = wv >> 4;
                const float* src = (z == 0) ? a.Wq : (z == 1) ? a.Wk : (z == 2) ? a.Wv : a.Wo;
                u16* dst = (z < 3) ? (a.wqkvt + (size_t)z * 1024 * 1024) : a.wot;
                const int row = t >> 2;
                const int c4 = (t & 3) * 16;
                const float* s = src + (size_t)(kb * 64 + row) * 1024 + nb2 * 64 + c4;
#pragma unroll
                for (int i = 0; i < 16; i += 4) {
                    float4 v = *(const float4*)(s + i);
                    ts[row * 65 + c4 + i] = v.x; ts[row * 65 + c4 + i + 1] = v.y;
                    ts[row * 65 + c4 + i + 2] = v.z; ts[row * 65 + c4 + i + 3] = v.w;
                }
                __syncthreads();
                u16* d = dst + (size_t)(nb2 * 64 + row) * 1024 + kb * 64 + c4;
                u16 tmp[16];
#pragma unroll
                for (int i = 0; i < 16; ++i) tmp[i] = f2bu(ts[(c4 + i) * 65 + row]);
                *(uint4*)(d) = *(uint4*)tmp;
                *(uint4*)(d + 8) = *((uint4*)tmp + 1);
            } else if (bx < 2048) {
                const int base = (bx - 1024) * 4096 + t * 4;
#pragma unroll
                for (int it = 0; it < 4; ++it) {
                    const int i = base + it * 1024;
                    float4 v = *(const float4*)(a.x + i);
                    uint32_t p0 = (uint32_t)f2bu(v.x) | ((uint32_t)f2bu(v.y) << 16);
                    uint32_t p1 = (uint32_t)f2bu(v.z) | ((uint32_t)f2bu(v.w) << 16);
                    uint2 o; o.x = p0; o.y = p1;
                    *(uint2*)(a.xb + i) = o;
                }
            } else {
#pragma unroll
                for (int it = 0; it < 4; ++it) {
                    const int i = t + it * 256;
                    a.bias_qkv[i] = a.bq[i];
                    a.bias_qkv[1024 + i] = a.bk[i];
                    a.bias_qkv[2048 + i] = a.bv[i];
                    a.bias_o[i] = a.bo[i];
                }
            }
        }
    }
    __threadfence();
    cg::this_grid().sync();

    // ================= phase 2: QKV GEMM + bias + fused-RoPE scatter (768 vblocks) =================
    {
        u16* As = smem;
        u16* Bs = smem + 128 * 64;
        const int wm = (wave >> 1) * 64, wn = (wave & 1) * 64;
        const int srow = t >> 3;
        const int scol = (((t & 7) ^ (srow & 7)) * 8);
        for (int v = blockIdx.x; v < 768; v += gdim) {
            const int by = v >> 5;
            const int row0 = (v & 31) * 128, col0 = by * 128;

            floatx4 acc[4][4] = {};
            const u16* gA = a.xb + (size_t)(row0 + srow) * 1024 + scol;
            const u16* gB = a.wqkvt + (size_t)(col0 + srow) * 1024 + scol;
            u16* lA = As + t * 8;
            u16* lB = Bs + t * 8;

            for (int k0 = 0; k0 < 1024; k0 += 64) {
                __syncthreads();
#pragma unroll
                for (int rr = 0; rr < 4; ++rr) {
                    glds16(gA + (size_t)(rr * 32) * 1024 + k0, lA + rr * 2048);
                    glds16(gB + (size_t)(rr * 32) * 1024 + k0, lB + rr * 2048);
                }
                __syncthreads();
#pragma unroll
                for (int c = 0; c < 2; ++c) {
                    short8 af[4], bfr[4];
                    const int swz = ((4 * c + quad) ^ (l16 & 7)) * 8;
#pragma unroll
                    for (int mi = 0; mi < 4; ++mi)
                        af[mi] = *(const short8*)(As + (wm + mi * 16 + l16) * 64 + swz);
#pragma unroll
                    for (int ni = 0; ni < 4; ++ni)
                        bfr[ni] = *(const short8*)(Bs + (wn + ni * 16 + l16) * 64 + swz);
#pragma unroll
                    for (int mi = 0; mi < 4; ++mi)
#pragma unroll
                        for (int ni = 0; ni < 4; ++ni)
                            acc[mi][ni] = __builtin_amdgcn_mfma_f32_16x16x32_bf16(
                                af[mi], bfr[ni], acc[mi][ni], 0, 0, 0);
                }
            }

#pragma unroll
            for (int ni = 0; ni < 4; ++ni) {
                float bval = a.bias_qkv[col0 + wn + ni * 16 + l16];
#pragma unroll
                for (int mi = 0; mi < 4; ++mi)
#pragma unroll
                    for (int r = 0; r < 4; ++r) acc[mi][ni][r] += bval;
            }

            __syncthreads();

            if (by < 16) {
                u16* Cs = smem;
#pragma unroll
                for (int mi = 0; mi < 4; ++mi)
#pragma unroll
                    for (int ni = 0; ni < 4; ++ni)
#pragma unroll
                        for (int r = 0; r < 4; ++r)
                            Cs[(wm + mi * 16 + quad * 4 + r) * 128 + wn + ni * 16 + l16] =
                                f2bu(acc[mi][ni][r]);
                __syncthreads();
                u16* dstbase = (by < 8) ? a.Qg : a.Kg;
                const bool rope_blk = (by == 0 || by == 8);
                const int orow = t >> 4;
                const int oc = (t & 15) * 8;
#pragma unroll
                for (int rr = 0; rr < 8; ++rr) {
                    const int row = rr * 16 + orow;
                    const int n = row0 + row;
                    const int b = n >> 11, nn = n & (N_ - 1);
                    const int c = col0 + oc;
                    const int h = (c & 1023) >> 6, d = c & 63;
                    uint4 val = *(const uint4*)(Cs + row * 128 + oc);
                    if (rope_blk && oc < 64) {
                        const float* f = a.freqs + (size_t)nn * HD_ + oc;
                        u16* pv = (u16*)&val;
#pragma unroll
                        for (int i = 0; i < 4; ++i) {
                            float fe = f[2 * i], fo = f[2 * i + 1];
                            float ve = bu2f(pv[2 * i]), vo = bu2f(pv[2 * i + 1]);
                            pv[2 * i]     = f2bu(ve * __cosf(fe) - vo * __sinf(fe));
                            pv[2 * i + 1] = f2bu(vo * __cosf(fo) + ve * __sinf(fo));
                        }
                    }
                    u16* dst = dstbase + (((size_t)(b * H_ + h)) * N_ + nn) * HD_ + d;
                    *(uint4*)dst = val;
                }
            } else {
                u16* Cs = smem;
#pragma unroll
                for (int mi = 0; mi < 4; ++mi)
#pragma unroll
                    for (int ni = 0; ni < 4; ++ni)
#pragma unroll
                        for (int r = 0; r < 4; ++r)
                            Cs[(wm + mi * 16 + quad * 4 + r) * 137 + wn + ni * 16 + l16] =
                                f2bu(acc[mi][ni][r]);
                __syncthreads();
                const int b = row0 >> 11;
                const int nn0 = row0 & (N_ - 1);
                const int n8 = (t & 15) * 8;
                const int d0 = t >> 4;
#pragma unroll
                for (int dd = 0; dd < 8; ++dd) {
                    const int d = d0 + dd * 16;
                    const int c = col0 + d;
                    const int h = (c & 1023) >> 6, dch = c & 63;
                    u16 tmp[8];
#pragma unroll
                    for (int i = 0; i < 8; ++i) tmp[i] = Cs[(n8 + i) * 137 + d];
                    u16* dst = a.Vtg + (((size_t)(b * H_ + h)) * HD_ + dch) * N_ + nn0 + n8;
                    *(uint4*)dst = *(const uint4*)tmp;
                }
            }
        }
    }
    __threadfence();
    cg::this_grid().sync();

    // ================= phase 3: sliding-window attention (1024 vblocks, round-6 form) =================
    {
        u16* Qs = smem;                 // 4096 u16
        u16* Ks = smem + 4096;
        u16* Vs = smem + 8192;
        u16* Ps = smem + 12288;         // 4*16*72
        const int srow = t >> 3;
        const int sch = ((t & 7) ^ (srow & 7)) * 8;
        const int swz0 = (quad ^ (l16 & 7)) * 8;
        const int swz1 = ((4 + quad) ^ (l16 & 7)) * 8;

        for (int v = blockIdx.x; v < 1024; v += gdim) {
            const int q0 = (v & 31) * 64;
            const int h = (v >> 5) & 15, b = v >> 9;
            const size_t bh = (size_t)(b * H_ + h);

            __syncthreads();            // smem reuse across grid-stride iters
            {
                const u16* qg = a.Qg + (bh * N_ + q0 + srow) * HD_ + sch;
                glds16(qg, Qs + t * 8);
                glds16(qg + 32 * HD_, Qs + 2048 + t * 8);
            }
            __syncthreads();
            const short8 aq0 = *(const short8*)(Qs + (wave * 16 + l16) * 64 + swz0);
            const short8 aq1 = *(const short8*)(Qs + (wave * 16 + l16) * 64 + swz1);

            const u16* kg0 = a.Kg + (bh * N_ + srow) * HD_ + sch;
            const u16* vg0 = a.Vtg + (bh * HD_ + srow) * N_ + sch;

            floatx4 oacc[4] = {};
            float lsum[4] = {0.f, 0.f, 0.f, 0.f};
            const int qrow_base = q0 + wave * 16 + quad * 4;

            const int t0 = (q0 >= 128) ? 0 : ((128 - q0) >> 6);
            const int t1 = min(5, (N_ + 128 - q0) >> 6);

            for (int tt = t0; tt < t1; ++tt) {
                const int j0 = q0 - 128 + tt * 64;
                const bool need_mask = (tt == 0) || (tt == 4);
                __syncthreads();
                glds16(kg0 + (size_t)j0 * HD_, Ks + t * 8);
                glds16(kg0 + (size_t)(j0 + 32) * HD_, Ks + 2048 + t * 8);
                glds16(vg0 + j0, Vs + t * 8);
                glds16(vg0 + j0 + 32 * N_, Vs + 2048 + t * 8);
                __syncthreads();

                floatx4 s[4] = {};
#pragma unroll
                for (int ni = 0; ni < 4; ++ni) {
                    short8 bk0 = *(const short8*)(Ks + (ni * 16 + l16) * 64 + swz0);
                    short8 bk1 = *(const short8*)(Ks + (ni * 16 + l16) * 64 + swz1);
                    s[ni] = __builtin_amdgcn_mfma_f32_16x16x32_bf16(aq0, bk0, s[ni], 0, 0, 0);
                    s[ni] = __builtin_amdgcn_mfma_f32_16x16x32_bf16(aq1, bk1, s[ni], 0, 0, 0);
                }
                if (need_mask) {
#pragma unroll
                    for (int ni = 0; ni < 4; ++ni)
#pragma unroll
                        for (int r = 0; r < 4; ++r) {
                            int dj = (j0 + ni * 16 + l16) - (qrow_base + r);
                            bool valid = (dj >= -HALF_W) && (dj <= HALF_W);
                            s[ni][r] = valid ? __expf(s[ni][r] * 0.125f) : 0.f;
                        }
                } else {
#pragma unroll
                    for (int ni = 0; ni < 4; ++ni)
#pragma unroll
                        for (int r = 0; r < 4; ++r) s[ni][r] = __expf(s[ni][r] * 0.125f);
                }
#pragma unroll
                for (int r = 0; r < 4; ++r)
                    lsum[r] += s[0][r] + s[1][r] + s[2][r] + s[3][r];
                u16* pw = Ps + wave * 16 * 72;
#pragma unroll
                for (int ni = 0; ni < 4; ++ni)
#pragma unroll
                    for (int r = 0; r < 4; ++r)
                        pw[(quad * 4 + r) * 72 + ni * 16 + l16] = f2bu(s[ni][r]);
#pragma unroll
                for (int c2 = 0; c2 < 2; ++c2) {
                    short8 pf = *(const short8*)(pw + l16 * 72 + 32 * c2 + quad * 8);
                    const int swz = c2 ? swz1 : swz0;
#pragma unroll
                    for (int ni = 0; ni < 4; ++ni) {
                        short8 vf = *(const short8*)(Vs + (ni * 16 + l16) * 64 + swz);
                        oacc[ni] = __builtin_amdgcn_mfma_f32_16x16x32_bf16(pf, vf, oacc[ni], 0, 0, 0);
                    }
                }
            }
            float linv[4];
#pragma unroll
            for (int r = 0; r < 4; ++r) {
                float vv = lsum[r];
                vv += __shfl_xor(vv, 1); vv += __shfl_xor(vv, 2);
                vv += __shfl_xor(vv, 4); vv += __shfl_xor(vv, 8);
                linv[r] = 1.0f / vv;
            }
            u16* outp = a.attn + ((size_t)b * N_ + q0 + wave * 16 + quad * 4) * INNER_ + h * HD_;
#pragma unroll
            for (int ni = 0; ni < 4; ++ni)
#pragma unroll
                for (int r = 0; r < 4; ++r)
                    outp[(size_t)r * INNER_ + ni * 16 + l16] = f2bu(oacc[ni][r] * linv[r]);
        }
    }
    __threadfence();
    cg::this_grid().sync();

    // ================= phase 4: out-proj GEMM (512 vblocks, tile 128x64) =================
    {
        u16* As = smem;                 // 8192 u16
        u16* Bs = smem + 8192;          // 4096 u16
        const int wm = (wave >> 1) * 64, wn = (wave & 1) * 32;
        const int srow = t >> 3;
        const int scol = (((t & 7) ^ (srow & 7)) * 8);
        for (int v = blockIdx.x; v < 512; v += gdim) {
            const int row0 = (v & 31) * 128, col0 = (v >> 5) * 64;

            floatx4 acc[4][2] = {};
            const u16* gA = a.attn + (size_t)(row0 + srow) * 1024 + scol;
            const u16* gB = a.wot + (size_t)(col0 + srow) * 1024 + scol;
            u16* lA = As + t * 8;
            u16* lB = Bs + t * 8;

            for (int k0 = 0; k0 < 1024; k0 += 64) {
                __syncthreads();
#pragma unroll
                for (int rr = 0; rr < 4; ++rr)
                    glds16(gA + (size_t)(rr * 32) * 1024 + k0, lA + rr * 2048);
#pragma unroll
                for (int rr = 0; rr < 2; ++rr)
                    glds16(gB + (size_t)(rr * 32) * 1024 + k0, lB + rr * 2048);
                __syncthreads();
#pragma unroll
                for (int c = 0; c < 2; ++c) {
                    short8 af[4], bfr[2];
                    const int swz = ((4 * c + quad) ^ (l16 & 7)) * 8;
#pragma unroll
                    for (int mi = 0; mi < 4; ++mi)
                        af[mi] = *(const short8*)(As + (wm + mi * 16 + l16) * 64 + swz);
#pragma unroll
                    for (int ni = 0; ni < 2; ++ni)
                        bfr[ni] = *(const short8*)(Bs + (wn + ni * 16 + l16) * 64 + swz);
#pragma unroll
                    for (int mi = 0; mi < 4; ++mi)
#pragma unroll
                        for (int ni = 0; ni < 2; ++ni)
                            acc[mi][ni] = __builtin_amdgcn_mfma_f32_16x16x32_bf16(
                                af[mi], bfr[ni], acc[mi][ni], 0, 0, 0);
                }
            }

            float bv2[2];
#pragma unroll
            for (int ni = 0; ni < 2; ++ni) bv2[ni] = a.bias_o[col0 + wn + ni * 16 + l16];

            __syncthreads();
            float* Cf = (float*)smem;
#pragma unroll
            for (int mi = 0; mi < 4; ++mi)
#pragma unroll
                for (int ni = 0; ni < 2; ++ni)
#pragma unroll
                    for (int r = 0; r < 4; ++r)
                        Cf[(wm + mi * 16 + quad * 4 + r) * 64 + wn + ni * 16 + l16] =
                            acc[mi][ni][r] + bv2[ni];
            __syncthreads();
            const int orow = t >> 4;
            const int oc = (t & 15) * 4;
#pragma unroll
            for (int rr = 0; rr < 8; ++rr) {
                const int row = rr * 16 + orow;
                *(float4*)(a.out + (size_t)(row0 + row) * 1024 + col0 + oc) =
                    *(const float4*)(Cf + row * 64 + oc);
            }
        }
    }
}

// =====================  host side  =====================
extern "C" void kernel_launch(void* const* d_in, const int* in_sizes, int n_in,
                              void* d_out, int out_size, void* d_ws, size_t ws_size,
                              hipStream_t stream) {
    char* w = (char*)d_ws;
    u16* xb       = (u16*)w;  w += (size_t)4096 * 1024 * 2;
    u16* wqkvt    = (u16*)w;  w += (size_t)3072 * 1024 * 2;
    u16* wot      = (u16*)w;  w += (size_t)1024 * 1024 * 2;
    float* bias_qkv = (float*)w; w += 3072 * 4;
    float* bias_o   = (float*)w; w += 1024 * 4;
    u16* Qb       = (u16*)w;  w += (size_t)B_ * H_ * N_ * HD_ * 2;
    u16* Kb       = (u16*)w;  w += (size_t)B_ * H_ * N_ * HD_ * 2;
    u16* Vtb      = (u16*)w;  w += (size_t)B_ * H_ * N_ * HD_ * 2;
    u16* attn     = (u16*)w;  w += (size_t)4096 * 1024 * 2;

    MegaArgs ma;
    ma.x     = (const float*)d_in[0];
    ma.freqs = (const float*)d_in[2];
    ma.Wq    = (const float*)d_in[3];
    ma.bq    = (const float*)d_in[4];
    ma.Wk    = (const float*)d_in[5];
    ma.bk    = (const float*)d_in[6];
    ma.Wv    = (const float*)d_in[7];
    ma.bv    = (const float*)d_in[8];
    ma.Wo    = (const float*)d_in[9];
    ma.bo    = (const float*)d_in[10];
    ma.xb = xb; ma.wqkvt = wqkvt; ma.wot = wot;
    ma.bias_qkv = bias_qkv; ma.bias_o = bias_o;
    ma.Qg = Qb; ma.Kg = Kb; ma.Vtg = Vtb; ma.attn = attn;
    ma.out = (float*)d_out;

    int nb = 0;
    if (hipOccupancyMaxActiveBlocksPerMultiprocessor(&nb, k_mega, 256, 0) != hipSuccess || nb < 1)
        nb = 1;
    int ncu = 256;
    int dev = 0;
    hipGetDevice(&dev);
    hipDeviceGetAttribute(&ncu, hipDeviceAttributeMultiprocessorCount, dev);
    long long cap = (long long)nb * (long long)ncu;
    int grid = (cap > 1024) ? 1024 : (int)cap;
    if (grid < 1) grid = 1;

    void* kp[] = { (void*)&ma };
    hipLaunchCooperativeKernel(k_mega, dim3(grid), dim3(256), kp, 0, stream);
}

// Round 9
// 163.363 us; speedup vs baseline: 3.3937x; 3.3937x over previous
//
#include <hip/hip_runtime.h>
#include <hip/hip_bf16.h>
#include <stdint.h>

#define B_ 2
#define N_ 2048
#define D_ 1024
#define H_ 16
#define HD_ 64
#define INNER_ 1024
#define HALF_W 128

typedef unsigned short u16;
typedef __attribute__((ext_vector_type(8))) short short8;
typedef __attribute__((ext_vector_type(4))) float floatx4;

// ---- bf16 <-> f32 bit helpers ----
__device__ inline u16 f2bu(float x) {
    union { float f; uint32_t u; } c; c.f = x;
    uint32_t u = c.u;
    uint32_t r = (u + 0x7FFFu + ((u >> 16) & 1u)) >> 16;
    return (u16)r;
}
__device__ inline float bu2f(u16 v) {
    union { float f; uint32_t u; } c; c.u = ((uint32_t)v) << 16;
    return c.f;
}

// ---- async global->LDS, 16B per lane (dest = wave-uniform base + lane*16) ----
__device__ inline void glds16(const u16* g, u16* l) {
    __builtin_amdgcn_global_load_lds(
        (const __attribute__((address_space(1))) uint32_t*)g,
        (__attribute__((address_space(3))) uint32_t*)l, 16, 0, 0);
}

// =========  prep: W transposes (blocks 0-1023) | x convert (1024-2047) | bias (2048)  =========
__global__ __launch_bounds__(256) void k_prep(const float* __restrict__ x,
                                              const float* __restrict__ Wq,
                                              const float* __restrict__ Wk,
                                              const float* __restrict__ Wv,
                                              const float* __restrict__ Wo,
                                              const float* __restrict__ bq,
                                              const float* __restrict__ bk,
                                              const float* __restrict__ bv,
                                              const float* __restrict__ bo,
                                              u16* __restrict__ xb,
                                              u16* __restrict__ wqkvt,
                                              u16* __restrict__ wot,
                                              float* __restrict__ bias_qkv,
                                              float* __restrict__ bias_o) {
    __shared__ float ts[64][65];
    const int bx = blockIdx.x;
    const int t = threadIdx.x;
    if (bx < 1024) {
        const int z = bx >> 8, w = bx & 255;
        const int kb = w & 15, nb = w >> 4;
        const float* src = (z == 0) ? Wq : (z == 1) ? Wk : (z == 2) ? Wv : Wo;
        u16* dst = (z < 3) ? (wqkvt + (size_t)z * 1024 * 1024) : wot;
        const int row = t >> 2;
        const int c4 = (t & 3) * 16;
        const float* s = src + (size_t)(kb * 64 + row) * 1024 + nb * 64 + c4;
#pragma unroll
        for (int i = 0; i < 16; i += 4) {
            float4 v = *(const float4*)(s + i);
            ts[row][c4 + i] = v.x; ts[row][c4 + i + 1] = v.y;
            ts[row][c4 + i + 2] = v.z; ts[row][c4 + i + 3] = v.w;
        }
        __syncthreads();
        const int n = row;
        u16* d = dst + (size_t)(nb * 64 + n) * 1024 + kb * 64 + c4;
        u16 tmp[16];
#pragma unroll
        for (int i = 0; i < 16; ++i) tmp[i] = f2bu(ts[c4 + i][n]);
        *(uint4*)(d) = *(uint4*)tmp;
        *(uint4*)(d + 8) = *((uint4*)tmp + 1);
    } else if (bx < 2048) {
        const int base = (bx - 1024) * 4096 + t * 4;
#pragma unroll
        for (int it = 0; it < 4; ++it) {
            const int i = base + it * 1024;
            float4 v = *(const float4*)(x + i);
            uint32_t p0 = (uint32_t)f2bu(v.x) | ((uint32_t)f2bu(v.y) << 16);
            uint32_t p1 = (uint32_t)f2bu(v.z) | ((uint32_t)f2bu(v.w) << 16);
            uint2 o; o.x = p0; o.y = p1;
            *(uint2*)(xb + i) = o;
        }
    } else {
#pragma unroll
        for (int it = 0; it < 4; ++it) {
            const int i = t + it * 256;
            bias_qkv[i] = bq[i];
            bias_qkv[1024 + i] = bk[i];
            bias_qkv[2048 + i] = bv[i];
            bias_o[i] = bo[i];
        }
    }
}

// ============  QKV GEMM + bias + fused-RoPE scatter epilogue  ============
// by 0-7 -> Q, 8-15 -> K (write [bh][n][d]; RoPE on head-0 cols in store path),
// by 16-23 -> V (write V^T [bh][d][n]).
__global__ __launch_bounds__(256, 4) void k_gemm_qkv(const u16* __restrict__ A,
                                                     const u16* __restrict__ Bt,
                                                     const float* __restrict__ bias,
                                                     const float* __restrict__ freqs,
                                                     u16* __restrict__ Qg,
                                                     u16* __restrict__ Kg,
                                                     u16* __restrict__ Vtg) {
    __shared__ u16 smem[128 * 137];
    u16* As = smem;
    u16* Bs = smem + 128 * 64;
    const int t = threadIdx.x;
    const int wave = t >> 6, lane = t & 63;
    const int quad = lane >> 4, l16 = lane & 15;
    const int wm = (wave >> 1) * 64, wn = (wave & 1) * 64;
    const int by = blockIdx.y;
    const int row0 = blockIdx.x * 128, col0 = by * 128;

    floatx4 acc[4][4] = {};

    const int srow = t >> 3;
    const int scol = (((t & 7) ^ (srow & 7)) * 8);
    const u16* gA = A + (size_t)(row0 + srow) * 1024 + scol;
    const u16* gB = Bt + (size_t)(col0 + srow) * 1024 + scol;
    u16* lA = As + t * 8;
    u16* lB = Bs + t * 8;

    for (int k0 = 0; k0 < 1024; k0 += 64) {
        __syncthreads();
#pragma unroll
        for (int rr = 0; rr < 4; ++rr) {
            glds16(gA + (size_t)(rr * 32) * 1024 + k0, lA + rr * 2048);
            glds16(gB + (size_t)(rr * 32) * 1024 + k0, lB + rr * 2048);
        }
        __syncthreads();
#pragma unroll
        for (int c = 0; c < 2; ++c) {
            short8 af[4], bfr[4];
            const int swz = ((4 * c + quad) ^ (l16 & 7)) * 8;
#pragma unroll
            for (int mi = 0; mi < 4; ++mi)
                af[mi] = *(const short8*)(As + (wm + mi * 16 + l16) * 64 + swz);
#pragma unroll
            for (int ni = 0; ni < 4; ++ni)
                bfr[ni] = *(const short8*)(Bs + (wn + ni * 16 + l16) * 64 + swz);
#pragma unroll
            for (int mi = 0; mi < 4; ++mi)
#pragma unroll
                for (int ni = 0; ni < 4; ++ni)
                    acc[mi][ni] = __builtin_amdgcn_mfma_f32_16x16x32_bf16(
                        af[mi], bfr[ni], acc[mi][ni], 0, 0, 0);
        }
    }

#pragma unroll
    for (int ni = 0; ni < 4; ++ni) {
        float bval = bias[col0 + wn + ni * 16 + l16];
#pragma unroll
        for (int mi = 0; mi < 4; ++mi)
#pragma unroll
            for (int r = 0; r < 4; ++r) acc[mi][ni][r] += bval;
    }

    __syncthreads();

    if (by < 16) {
        u16* Cs = smem;
#pragma unroll
        for (int mi = 0; mi < 4; ++mi)
#pragma unroll
            for (int ni = 0; ni < 4; ++ni)
#pragma unroll
                for (int r = 0; r < 4; ++r)
                    Cs[(wm + mi * 16 + quad * 4 + r) * 128 + wn + ni * 16 + l16] =
                        f2bu(acc[mi][ni][r]);
        __syncthreads();
        u16* dstbase = (by < 8) ? Qg : Kg;
        const bool rope_blk = (by == 0 || by == 8);
        const int orow = t >> 4;
        const int oc = (t & 15) * 8;
#pragma unroll
        for (int rr = 0; rr < 8; ++rr) {
            const int row = rr * 16 + orow;
            const int n = row0 + row;
            const int b = n >> 11, nn = n & (N_ - 1);
            const int c = col0 + oc;
            const int h = (c & 1023) >> 6, d = c & 63;
            uint4 val = *(const uint4*)(Cs + row * 128 + oc);
            if (rope_blk && oc < 64) {
                const float* f = freqs + (size_t)nn * HD_ + oc;
                u16* pv = (u16*)&val;
#pragma unroll
                for (int i = 0; i < 4; ++i) {
                    float fe = f[2 * i], fo = f[2 * i + 1];
                    float ve = bu2f(pv[2 * i]), vo = bu2f(pv[2 * i + 1]);
                    pv[2 * i]     = f2bu(ve * __cosf(fe) - vo * __sinf(fe));
                    pv[2 * i + 1] = f2bu(vo * __cosf(fo) + ve * __sinf(fo));
                }
            }
            u16* dst = dstbase + (((size_t)(b * H_ + h)) * N_ + nn) * HD_ + d;
            *(uint4*)dst = val;
        }
    } else {
        u16* Cs = smem;
#pragma unroll
        for (int mi = 0; mi < 4; ++mi)
#pragma unroll
            for (int ni = 0; ni < 4; ++ni)
#pragma unroll
                for (int r = 0; r < 4; ++r)
                    Cs[(wm + mi * 16 + quad * 4 + r) * 137 + wn + ni * 16 + l16] =
                        f2bu(acc[mi][ni][r]);
        __syncthreads();
        const int b = row0 >> 11;
        const int nn0 = row0 & (N_ - 1);
        const int n8 = (t & 15) * 8;
        const int d0 = t >> 4;
#pragma unroll
        for (int dd = 0; dd < 8; ++dd) {
            const int d = d0 + dd * 16;
            const int c = col0 + d;
            const int h = (c & 1023) >> 6, dch = c & 63;
            u16 tmp[8];
#pragma unroll
            for (int i = 0; i < 8; ++i) tmp[i] = Cs[(n8 + i) * 137 + d];
            u16* dst = Vtg + (((size_t)(b * H_ + h)) * HD_ + dch) * N_ + nn0 + n8;
            *(uint4*)dst = *(const uint4*)tmp;
        }
    }
}

// ============  out-proj GEMM: C(fp32) = attn * wot^T + bias; tile 128x64  ============
__global__ __launch_bounds__(256, 4) void k_gemm_out(const u16* __restrict__ A,
                                                     const u16* __restrict__ Bt,
                                                     const float* __restrict__ bias,
                                                     float* __restrict__ C) {
    __shared__ u16 smem[16384];
    u16* As = smem;
    u16* Bs = smem + 8192;
    const int t = threadIdx.x;
    const int wave = t >> 6, lane = t & 63;
    const int quad = lane >> 4, l16 = lane & 15;
    const int wm = (wave >> 1) * 64, wn = (wave & 1) * 32;
    const int row0 = blockIdx.x * 128, col0 = blockIdx.y * 64;

    floatx4 acc[4][2] = {};

    const int srow = t >> 3;
    const int scol = (((t & 7) ^ (srow & 7)) * 8);
    const u16* gA = A + (size_t)(row0 + srow) * 1024 + scol;
    const u16* gB = Bt + (size_t)(col0 + srow) * 1024 + scol;
    u16* lA = As + t * 8;
    u16* lB = Bs + t * 8;

    for (int k0 = 0; k0 < 1024; k0 += 64) {
        __syncthreads();
#pragma unroll
        for (int rr = 0; rr < 4; ++rr)
            glds16(gA + (size_t)(rr * 32) * 1024 + k0, lA + rr * 2048);
#pragma unroll
        for (int rr = 0; rr < 2; ++rr)
            glds16(gB + (size_t)(rr * 32) * 1024 + k0, lB + rr * 2048);
        __syncthreads();
#pragma unroll
        for (int c = 0; c < 2; ++c) {
            short8 af[4], bfr[2];
            const int swz = ((4 * c + quad) ^ (l16 & 7)) * 8;
#pragma unroll
            for (int mi = 0; mi < 4; ++mi)
                af[mi] = *(const short8*)(As + (wm + mi * 16 + l16) * 64 + swz);
#pragma unroll
            for (int ni = 0; ni < 2; ++ni)
                bfr[ni] = *(const short8*)(Bs + (wn + ni * 16 + l16) * 64 + swz);
#pragma unroll
            for (int mi = 0; mi < 4; ++mi)
#pragma unroll
                for (int ni = 0; ni < 2; ++ni)
                    acc[mi][ni] = __builtin_amdgcn_mfma_f32_16x16x32_bf16(
                        af[mi], bfr[ni], acc[mi][ni], 0, 0, 0);
        }
    }

    float bv2[2];
#pragma unroll
    for (int ni = 0; ni < 2; ++ni) bv2[ni] = bias[col0 + wn + ni * 16 + l16];

    __syncthreads();
    float* Cf = (float*)smem;
#pragma unroll
    for (int mi = 0; mi < 4; ++mi)
#pragma unroll
        for (int ni = 0; ni < 2; ++ni)
#pragma unroll
            for (int r = 0; r < 4; ++r)
                Cf[(wm + mi * 16 + quad * 4 + r) * 64 + wn + ni * 16 + l16] =
                    acc[mi][ni][r] + bv2[ni];
    __syncthreads();
    const int orow = t >> 4;
    const int oc = (t & 15) * 4;
#pragma unroll
    for (int rr = 0; rr < 8; ++rr) {
        const int row = rr * 16 + orow;
        *(float4*)(C + (size_t)(row0 + row) * 1024 + col0 + oc) =
            *(const float4*)(Cf + row * 64 + oc);
    }
}

// ==========  sliding-window flash attention (no-max softmax, deferred sum)  ==========
// block = (64 q-rows, h, b); staging via global_load_lds + XOR swizzle.
__global__ __launch_bounds__(256, 4) void k_attn(const u16* __restrict__ Qg,
                                                 const u16* __restrict__ Kg,
                                                 const u16* __restrict__ Vtg,
                                                 u16* __restrict__ Og) {
    __shared__ u16 Qs[64 * 64];
    __shared__ u16 Ks[64 * 64];
    __shared__ u16 Vs[64 * 64];
    __shared__ u16 Ps[4 * 16 * 72];
    const int t = threadIdx.x;
    const int wave = t >> 6, lane = t & 63;
    const int quad = lane >> 4, l16 = lane & 15;
    const int q0 = blockIdx.x * 64;
    const int h = blockIdx.y, b = blockIdx.z;
    const size_t bh = (size_t)(b * H_ + h);

    const int srow = t >> 3;
    const int sch = ((t & 7) ^ (srow & 7)) * 8;

    {
        const u16* qg = Qg + (bh * N_ + q0 + srow) * HD_ + sch;
        glds16(qg, Qs + t * 8);
        glds16(qg + 32 * HD_, Qs + 2048 + t * 8);
    }
    __syncthreads();
    const int swz0 = (quad ^ (l16 & 7)) * 8;
    const int swz1 = ((4 + quad) ^ (l16 & 7)) * 8;
    const short8 aq0 = *(const short8*)(Qs + (wave * 16 + l16) * 64 + swz0);
    const short8 aq1 = *(const short8*)(Qs + (wave * 16 + l16) * 64 + swz1);

    const u16* kg0 = Kg + (bh * N_ + srow) * HD_ + sch;
    const u16* vg0 = Vtg + (bh * HD_ + srow) * N_ + sch;

    floatx4 oacc[4] = {};
    float lsum[4] = {0.f, 0.f, 0.f, 0.f};
    const int qrow_base = q0 + wave * 16 + quad * 4;
    const float SC = 0.18033688f;   // 0.125 * log2(e); exp(s/8) == exp2(s*SC)

    const int t0 = (q0 >= 128) ? 0 : ((128 - q0) >> 6);
    const int t1 = min(5, (N_ + 128 - q0) >> 6);

    for (int tt = t0; tt < t1; ++tt) {
        const int j0 = q0 - 128 + tt * 64;
        const bool need_mask = (tt == 0) || (tt == 4);
        __syncthreads();
        glds16(kg0 + (size_t)j0 * HD_, Ks + t * 8);
        glds16(kg0 + (size_t)(j0 + 32) * HD_, Ks + 2048 + t * 8);
        glds16(vg0 + j0, Vs + t * 8);
        glds16(vg0 + j0 + 32 * N_, Vs + 2048 + t * 8);
        __syncthreads();

        floatx4 s[4] = {};
#pragma unroll
        for (int ni = 0; ni < 4; ++ni) {
            short8 bk0 = *(const short8*)(Ks + (ni * 16 + l16) * 64 + swz0);
            short8 bk1 = *(const short8*)(Ks + (ni * 16 + l16) * 64 + swz1);
            s[ni] = __builtin_amdgcn_mfma_f32_16x16x32_bf16(aq0, bk0, s[ni], 0, 0, 0);
            s[ni] = __builtin_amdgcn_mfma_f32_16x16x32_bf16(aq1, bk1, s[ni], 0, 0, 0);
        }
        if (need_mask) {
#pragma unroll
            for (int ni = 0; ni < 4; ++ni)
#pragma unroll
                for (int r = 0; r < 4; ++r) {
                    int dj = (j0 + ni * 16 + l16) - (qrow_base + r);
                    bool valid = (dj >= -HALF_W) && (dj <= HALF_W);
                    s[ni][r] = valid ? exp2f(s[ni][r] * SC) : 0.f;
                }
        } else {
#pragma unroll
            for (int ni = 0; ni < 4; ++ni)
#pragma unroll
                for (int r = 0; r < 4; ++r) s[ni][r] = exp2f(s[ni][r] * SC);
        }
#pragma unroll
        for (int r = 0; r < 4; ++r)
            lsum[r] += s[0][r] + s[1][r] + s[2][r] + s[3][r];
        u16* pw = Ps + wave * 16 * 72;
#pragma unroll
        for (int ni = 0; ni < 4; ++ni)
#pragma unroll
            for (int r = 0; r < 4; ++r)
                pw[(quad * 4 + r) * 72 + ni * 16 + l16] = f2bu(s[ni][r]);
#pragma unroll
        for (int c2 = 0; c2 < 2; ++c2) {
            short8 pf = *(const short8*)(pw + l16 * 72 + 32 * c2 + quad * 8);
            const int swz = c2 ? swz1 : swz0;
#pragma unroll
            for (int ni = 0; ni < 4; ++ni) {
                short8 vf = *(const short8*)(Vs + (ni * 16 + l16) * 64 + swz);
                oacc[ni] = __builtin_amdgcn_mfma_f32_16x16x32_bf16(pf, vf, oacc[ni], 0, 0, 0);
            }
        }
    }
    float linv[4];
#pragma unroll
    for (int r = 0; r < 4; ++r) {
        float v = lsum[r];
        v += __shfl_xor(v, 1); v += __shfl_xor(v, 2);
        v += __shfl_xor(v, 4); v += __shfl_xor(v, 8);
        linv[r] = 1.0f / v;
    }
    u16* outp = Og + ((size_t)b * N_ + q0 + wave * 16 + quad * 4) * INNER_ + h * HD_;
#pragma unroll
    for (int ni = 0; ni < 4; ++ni)
#pragma unroll
        for (int r = 0; r < 4; ++r)
            outp[(size_t)r * INNER_ + ni * 16 + l16] = f2bu(oacc[ni][r] * linv[r]);
}

// =====================  host side  =====================
extern "C" void kernel_launch(void* const* d_in, const int* in_sizes, int n_in,
                              void* d_out, int out_size, void* d_ws, size_t ws_size,
                              hipStream_t stream) {
    const float* x     = (const float*)d_in[0];
    const float* freqs = (const float*)d_in[2];
    const float* Wq    = (const float*)d_in[3];
    const float* bq    = (const float*)d_in[4];
    const float* Wk    = (const float*)d_in[5];
    const float* bk    = (const float*)d_in[6];
    const float* Wv    = (const float*)d_in[7];
    const float* bv    = (const float*)d_in[8];
    const float* Wo    = (const float*)d_in[9];
    const float* bo    = (const float*)d_in[10];

    char* w = (char*)d_ws;
    u16* xb       = (u16*)w;  w += (size_t)4096 * 1024 * 2;
    u16* wqkvt    = (u16*)w;  w += (size_t)3072 * 1024 * 2;
    u16* wot      = (u16*)w;  w += (size_t)1024 * 1024 * 2;
    float* bias_qkv = (float*)w; w += 3072 * 4;
    float* bias_o   = (float*)w; w += 1024 * 4;
    u16* Qb       = (u16*)w;  w += (size_t)B_ * H_ * N_ * HD_ * 2;
    u16* Kb       = (u16*)w;  w += (size_t)B_ * H_ * N_ * HD_ * 2;
    u16* Vtb      = (u16*)w;  w += (size_t)B_ * H_ * N_ * HD_ * 2;
    u16* attn     = (u16*)w;  w += (size_t)4096 * 1024 * 2;

    k_prep<<<2049, 256, 0, stream>>>(x, Wq, Wk, Wv, Wo, bq, bk, bv, bo,
                                     xb, wqkvt, wot, bias_qkv, bias_o);
    k_gemm_qkv<<<dim3(32, 24), 256, 0, stream>>>(xb, wqkvt, bias_qkv, freqs,
                                                 Qb, Kb, Vtb);
    k_attn<<<dim3(32, 16, 2), 256, 0, stream>>>(Qb, Kb, Vtb, attn);
    k_gemm_out<<<dim3(32, 16), 256, 0, stream>>>(attn, wot, bias_o, (float*)d_out);
}